// Round 7
// baseline (2707.617 us; speedup 1.0000x reference)
//
#include <hip/hip_runtime.h>

#define TT 4000   // timesteps
#define HH 64     // hidden
#define NB 256    // batch
#define EE 128    // fc out
#define KQ 16     // per-thread reduction quarter (16 halves)

typedef __attribute__((ext_vector_type(2))) _Float16 h2;
typedef __attribute__((ext_vector_type(8))) _Float16 h8;

// Fast activations: v_exp_f32 + v_rcp_f32. ~1e-6 rel err vs 3.4e-3 threshold.
__device__ __forceinline__ float fsig(float x) {
    return __builtin_amdgcn_rcpf(1.f + __expf(-x));
}
__device__ __forceinline__ float ftanh(float x) {
    return fmaf(2.f, __builtin_amdgcn_rcpf(1.f + __expf(-2.f * x)), -1.f);
}

#if __has_builtin(__builtin_amdgcn_fdot2)
#define FDOT2(a, b, c) __builtin_amdgcn_fdot2((a), (b), (c), false)
#else
#define FDOT2(a, b, c) fmaf((float)(a).x, (float)(b).x, fmaf((float)(a).y, (float)(b).y, (c)))
#endif

// Extract packed f16 pair i from an h8 register (register-aliasing, no memory).
#define H2AT(V, i) (h2{(V)[2*(i)], (V)[2*(i)+1]})

// One block (1024 thr) per batch element; threads 4r..4r+3 own gate row r
// (i,f,g,o over r=0..255), k-quarters of 16.
//
// R3-R6 unified finding: every variant with per-thread weight ARRAYS ends up
// re-reading ~196 KB/block/step of weights from L2 (arrays -> scratch alloca
// or sunk loads), ~1650 cyc/step = measured dur in all rounds. This version
// uses 24 individually-NAMED h2 scalars (straight-line, no indexing -> SROA
// guaranteed) + ONE asm volatile remat-fence with all weights as "+v"
// operands. Live set ~60 regs vs 128 budget (launch_bounds 1024,4).
//
// Layer pipelining (verified R3-R6): iteration t computes L0 gates(t) from
// h0(t-1) and L1 gates(t-1) from {h1(t-2), h0(t-1)}; wave0 updates c0(t),
// wave1 updates c1(t-1). 2 barriers/step.
__global__ __launch_bounds__(1024, 4)
void lstm2_fc_kernel(const float* __restrict__ x,      // [B, T, 1]
                     const float* __restrict__ W_ih0,  // [256, 1]
                     const float* __restrict__ W_hh0,  // [256, 64]
                     const float* __restrict__ b_ih0,  // [256]
                     const float* __restrict__ b_hh0,  // [256]
                     const float* __restrict__ W_ih1,  // [256, 64]
                     const float* __restrict__ W_hh1,  // [256, 64]
                     const float* __restrict__ b_ih1,  // [256]
                     const float* __restrict__ b_hh1,  // [256]
                     const float* __restrict__ W_fc,   // [128, 64]
                     const float* __restrict__ b_fc,   // [128]
                     float* __restrict__ out)          // [B, 128]
{
    const int b   = blockIdx.x;
    const int tid = threadIdx.x;    // 0..1023
    const int r   = tid >> 2;       // gate row 0..255
    const int q   = tid & 3;        // k-quarter

    __shared__ float x_s[TT];                       // 16 KB
    __shared__ __align__(16) _Float16 h0_h[HH];     // h0(t-1), fp16
    __shared__ __align__(16) _Float16 h1_h[HH];     // h1(t-2), fp16
    __shared__ float g0_s[4 * HH];                  // L0 gate activations (fp32)
    __shared__ float g1_s[4 * HH];                  // L1 gate activations (fp32)

    for (int t = tid; t < TT; t += 1024) x_s[t] = x[(size_t)b * TT + t];

    // --- Named-scalar weight load (3 quarter-rows -> 24 h2), straight-line ---
    const float4* p0 = (const float4*)(W_hh0 + r * HH + q * KQ);
    const float4* p1 = (const float4*)(W_ih1 + r * HH + q * KQ);
    const float4* p2 = (const float4*)(W_hh1 + r * HH + q * KQ);
    float4 u0 = p0[0], u1 = p0[1], u2 = p0[2], u3 = p0[3];
    float4 v0 = p1[0], v1 = p1[1], v2 = p1[2], v3 = p1[3];
    float4 t0 = p2[0], t1 = p2[1], t2 = p2[2], t3 = p2[3];
    h2 A0 = h2{(_Float16)u0.x, (_Float16)u0.y}, A1 = h2{(_Float16)u0.z, (_Float16)u0.w};
    h2 A2 = h2{(_Float16)u1.x, (_Float16)u1.y}, A3 = h2{(_Float16)u1.z, (_Float16)u1.w};
    h2 A4 = h2{(_Float16)u2.x, (_Float16)u2.y}, A5 = h2{(_Float16)u2.z, (_Float16)u2.w};
    h2 A6 = h2{(_Float16)u3.x, (_Float16)u3.y}, A7 = h2{(_Float16)u3.z, (_Float16)u3.w};
    h2 B0 = h2{(_Float16)v0.x, (_Float16)v0.y}, B1 = h2{(_Float16)v0.z, (_Float16)v0.w};
    h2 B2 = h2{(_Float16)v1.x, (_Float16)v1.y}, B3 = h2{(_Float16)v1.z, (_Float16)v1.w};
    h2 B4 = h2{(_Float16)v2.x, (_Float16)v2.y}, B5 = h2{(_Float16)v2.z, (_Float16)v2.w};
    h2 B6 = h2{(_Float16)v3.x, (_Float16)v3.y}, B7 = h2{(_Float16)v3.z, (_Float16)v3.w};
    h2 C0 = h2{(_Float16)t0.x, (_Float16)t0.y}, C1 = h2{(_Float16)t0.z, (_Float16)t0.w};
    h2 C2 = h2{(_Float16)t1.x, (_Float16)t1.y}, C3 = h2{(_Float16)t1.z, (_Float16)t1.w};
    h2 C4 = h2{(_Float16)t2.x, (_Float16)t2.y}, C5 = h2{(_Float16)t2.z, (_Float16)t2.w};
    h2 C6 = h2{(_Float16)t3.x, (_Float16)t3.y}, C7 = h2{(_Float16)t3.z, (_Float16)t3.w};

    float wx  = W_ih0[r];
    float bb0 = b_ih0[r] + b_hh0[r];
    float bb1 = b_ih1[r] + b_hh1[r];

    // ONE remat fence: everything loop-invariant becomes opaque register data.
    asm volatile("" : "+v"(A0), "+v"(A1), "+v"(A2), "+v"(A3),
                      "+v"(A4), "+v"(A5), "+v"(A6), "+v"(A7),
                      "+v"(B0), "+v"(B1), "+v"(B2), "+v"(B3),
                      "+v"(B4), "+v"(B5), "+v"(B6), "+v"(B7),
                      "+v"(C0), "+v"(C1), "+v"(C2), "+v"(C3),
                      "+v"(C4), "+v"(C5), "+v"(C6), "+v"(C7),
                      "+v"(wx), "+v"(bb0), "+v"(bb1));

    const int gate_type = r >> 6;      // wave-uniform (16 rows/wave)

    float c0 = 0.f, c1 = 0.f;          // c0 live in wave0, c1 in wave1
    if (tid < HH) { h0_h[tid] = (_Float16)0.f; h1_h[tid] = (_Float16)0.f; }
    __syncthreads();

    const h8* h0v = (const h8*)h0_h;   // 8 halves per h8; HH=64 -> 8 h8
    const h8* h1v = (const h8*)h1_h;

    // TT+1 iterations: L0 active for t<TT, L1 (one step behind) for t>0.
    for (int t = 0; t <= TT; ++t) {
        const float xt = x_s[(t < TT) ? t : 0];   // broadcast; unused at t=TT

        // This thread's 16-half slices of h0/h1: two b128 reads each.
        h8 Ha = h0v[q * 2 + 0], Hb = h0v[q * 2 + 1];
        h8 Ga = h1v[q * 2 + 0], Gb = h1v[q * 2 + 1];

        float acc0 = (q == 0) ? fmaf(xt, wx, bb0) : 0.f;
        float a1a  = (q == 0) ? bb1 : 0.f;        // W_ih1 . h0 chain
        float a1b  = 0.f;                         // W_hh1 . h1 chain

        acc0 = FDOT2(A0, H2AT(Ha, 0), acc0);
        acc0 = FDOT2(A1, H2AT(Ha, 1), acc0);
        acc0 = FDOT2(A2, H2AT(Ha, 2), acc0);
        acc0 = FDOT2(A3, H2AT(Ha, 3), acc0);
        acc0 = FDOT2(A4, H2AT(Hb, 0), acc0);
        acc0 = FDOT2(A5, H2AT(Hb, 1), acc0);
        acc0 = FDOT2(A6, H2AT(Hb, 2), acc0);
        acc0 = FDOT2(A7, H2AT(Hb, 3), acc0);

        a1a = FDOT2(B0, H2AT(Ha, 0), a1a);
        a1a = FDOT2(B1, H2AT(Ha, 1), a1a);
        a1a = FDOT2(B2, H2AT(Ha, 2), a1a);
        a1a = FDOT2(B3, H2AT(Ha, 3), a1a);
        a1a = FDOT2(B4, H2AT(Hb, 0), a1a);
        a1a = FDOT2(B5, H2AT(Hb, 1), a1a);
        a1a = FDOT2(B6, H2AT(Hb, 2), a1a);
        a1a = FDOT2(B7, H2AT(Hb, 3), a1a);

        a1b = FDOT2(C0, H2AT(Ga, 0), a1b);
        a1b = FDOT2(C1, H2AT(Ga, 1), a1b);
        a1b = FDOT2(C2, H2AT(Ga, 2), a1b);
        a1b = FDOT2(C3, H2AT(Ga, 3), a1b);
        a1b = FDOT2(C4, H2AT(Gb, 0), a1b);
        a1b = FDOT2(C5, H2AT(Gb, 1), a1b);
        a1b = FDOT2(C6, H2AT(Gb, 2), a1b);
        a1b = FDOT2(C7, H2AT(Gb, 3), a1b);

        float acc1 = a1a + a1b;

        // Quad reduce (lanes 4r..4r+3, DPP).
        acc0 += __shfl_xor(acc0, 1);
        acc0 += __shfl_xor(acc0, 2);
        acc1 += __shfl_xor(acc1, 1);
        acc1 += __shfl_xor(acc1, 2);
        if (q == 0) {
            g0_s[r] = (gate_type == 2) ? ftanh(acc0) : fsig(acc0);
            g1_s[r] = (gate_type == 2) ? ftanh(acc1) : fsig(acc1);
        }
        __syncthreads();                          // B1: gates visible; h reads drained

        if (tid < HH) {                           // wave 0: L0 cell (time t)
            if (t < TT) {
                float iv = g0_s[tid];
                float fv = g0_s[HH + tid];
                float gv = g0_s[2 * HH + tid];
                float ov = g0_s[3 * HH + tid];
                c0 = fmaf(fv, c0, iv * gv);
                h0_h[tid] = (_Float16)(ov * ftanh(c0));
            }
        } else if (tid < 2 * HH) {                // wave 1: L1 cell (time t-1)
            if (t > 0) {
                int j = tid - HH;
                float iv = g1_s[j];
                float fv = g1_s[HH + j];
                float gv = g1_s[2 * HH + j];
                float ov = g1_s[3 * HH + j];
                c1 = fmaf(fv, c1, iv * gv);
                h1_h[j] = (_Float16)(ov * ftanh(c1));
            }
        }
        __syncthreads();                          // B2: new h0/h1 visible
    }

    // FC on final h1 = h1(TT-1): out[b, e] = W_fc[e,:] . h1 + b_fc[e]
    if (tid < EE) {
        float acc = b_fc[tid];
        const float4* wf = (const float4*)(W_fc + tid * HH);
        #pragma unroll
        for (int k = 0; k < HH / 4; ++k) {
            float4 v = wf[k];
            acc = fmaf(v.x, (float)h1_h[4*k+0], acc);
            acc = fmaf(v.y, (float)h1_h[4*k+1], acc);
            acc = fmaf(v.z, (float)h1_h[4*k+2], acc);
            acc = fmaf(v.w, (float)h1_h[4*k+3], acc);
        }
        out[(size_t)b * EE + tid] = acc;
    }
}

extern "C" void kernel_launch(void* const* d_in, const int* in_sizes, int n_in,
                              void* d_out, int out_size, void* d_ws, size_t ws_size,
                              hipStream_t stream) {
    const float* x     = (const float*)d_in[0];
    const float* W_ih0 = (const float*)d_in[1];
    const float* W_hh0 = (const float*)d_in[2];
    const float* b_ih0 = (const float*)d_in[3];
    const float* b_hh0 = (const float*)d_in[4];
    const float* W_ih1 = (const float*)d_in[5];
    const float* W_hh1 = (const float*)d_in[6];
    const float* b_ih1 = (const float*)d_in[7];
    const float* b_hh1 = (const float*)d_in[8];
    const float* W_fc  = (const float*)d_in[9];
    const float* b_fc  = (const float*)d_in[10];
    float* out = (float*)d_out;

    lstm2_fc_kernel<<<dim3(NB), dim3(1024), 0, stream>>>(
        x, W_ih0, W_hh0, b_ih0, b_hh0, W_ih1, W_hh1, b_ih1, b_hh1, W_fc, b_fc, out);
}

// Round 8
// 2442.912 us; speedup vs baseline: 1.1084x; 1.1084x over previous
//
#include <hip/hip_runtime.h>

#define TT 4000   // timesteps
#define HH 64     // hidden
#define NB 256    // batch
#define EE 128    // fc out

typedef __attribute__((ext_vector_type(2))) _Float16 h2;
typedef __attribute__((ext_vector_type(8))) _Float16 h8;

__device__ __forceinline__ float ftanh(float x) {
    return fmaf(2.f, __builtin_amdgcn_rcpf(1.f + __expf(-2.f * x)), -1.f);
}

#if __has_builtin(__builtin_amdgcn_fdot2)
#define FDOT2(a, b, c) __builtin_amdgcn_fdot2((a), (b), (c), false)
#else
#define FDOT2(a, b, c) fmaf((float)(a).x, (float)(b).x, fmaf((float)(a).y, (float)(b).y, (c)))
#endif

// h2 sub-extract from h8 register (shufflevector -> sub-register, no memory).
#define H2V(V, i) (__builtin_shufflevector((V), (V), 2 * (i), 2 * (i) + 1))

// DPP quad-perm butterfly adds (VALU, not LDS pipe). 0xB1=[1,0,3,2], 0x4E=[2,3,0,1].
__device__ __forceinline__ float dpp_add_xor1(float v) {
    int m = __builtin_amdgcn_update_dpp(0, __float_as_int(v), 0xB1, 0xF, 0xF, true);
    return v + __int_as_float(m);
}
__device__ __forceinline__ float dpp_add_xor2(float v) {
    int m = __builtin_amdgcn_update_dpp(0, __float_as_int(v), 0x4E, 0xF, 0xF, true);
    return v + __int_as_float(m);
}

// One block (1024 thr) per batch element. tid = n*16 + j*4 + s:
//   n = h-index 0..63, j = gate (0:i 1:f 2:g 3:o), s = k-quarter (16 k each).
// Each wave owns 4 complete h-indices (all 4 gates, all 4 k-quarters), so the
// cell update is IN-WAVE: after the DPP s-butterfly, gates i,f,g,o of index n
// sit in lanes j=0..3 -> 3 shfl_xor gathers, no LDS gate round trip, and only
// ONE barrier/step (h exchange, double-buffered).
//
// R7 falsified the weight-refetch theory (weights register-resident at
// VGPR=36, dur unchanged): the 1620 cyc/step floor was the 2-barrier phase
// structure (2-wave serial cell phase + 2 drains). This removes it.
//
// Layer pipelining (verified R3-R7): iter t computes L0 gates(t) from h0(t-1)
// and L1 gates(t-1) from {h1(t-2), h0(t-1)}; lanes s<2 update c0(t), s>=2
// update c1(t-1). Both h buffers zero-inited; L0 write skipped at t=TT, L1 at
// t=0 (keeps h1(-1)=0).
__global__ __launch_bounds__(1024, 4)
void lstm2_fc_kernel(const float* __restrict__ x,      // [B, T, 1]
                     const float* __restrict__ W_ih0,  // [256, 1]
                     const float* __restrict__ W_hh0,  // [256, 64]
                     const float* __restrict__ b_ih0,  // [256]
                     const float* __restrict__ b_hh0,  // [256]
                     const float* __restrict__ W_ih1,  // [256, 64]
                     const float* __restrict__ W_hh1,  // [256, 64]
                     const float* __restrict__ b_ih1,  // [256]
                     const float* __restrict__ b_hh1,  // [256]
                     const float* __restrict__ W_fc,   // [128, 64]
                     const float* __restrict__ b_fc,   // [128]
                     float* __restrict__ out)          // [B, 128]
{
    const int b    = blockIdx.x;
    const int tid  = threadIdx.x;     // 0..1023
    const int lane = tid & 63;
    const int n    = tid >> 4;        // h-index 0..63
    const int jj   = (lane >> 2) & 3; // gate
    const int ss   = lane & 3;        // k-quarter

    __shared__ float x_s[TT];                         // 16 KB
    __shared__ __align__(16) _Float16 hbuf[2][2 * HH]; // [parity][h0|h1], fp16

    for (int t = tid; t < TT; t += 1024) x_s[t] = x[(size_t)b * TT + t];
    if (tid < 4 * HH) ((_Float16*)hbuf)[tid] = (_Float16)0.f;

    const int row = jj * HH + n;      // gate row in [0,256)
    // --- Named-scalar weight load: 3 sixteen-wide slices -> 24 h2 ---
    const float4* p0 = (const float4*)(W_hh0 + row * HH + ss * 16);
    const float4* p1 = (const float4*)(W_ih1 + row * HH + ss * 16);
    const float4* p2 = (const float4*)(W_hh1 + row * HH + ss * 16);
    float4 u0 = p0[0], u1 = p0[1], u2 = p0[2], u3 = p0[3];
    float4 v0 = p1[0], v1_ = p1[1], v2_ = p1[2], v3_ = p1[3];
    float4 t0 = p2[0], t1 = p2[1], t2 = p2[2], t3 = p2[3];
    h2 A0 = h2{(_Float16)u0.x, (_Float16)u0.y}, A1 = h2{(_Float16)u0.z, (_Float16)u0.w};
    h2 A2 = h2{(_Float16)u1.x, (_Float16)u1.y}, A3 = h2{(_Float16)u1.z, (_Float16)u1.w};
    h2 A4 = h2{(_Float16)u2.x, (_Float16)u2.y}, A5 = h2{(_Float16)u2.z, (_Float16)u2.w};
    h2 A6 = h2{(_Float16)u3.x, (_Float16)u3.y}, A7 = h2{(_Float16)u3.z, (_Float16)u3.w};
    h2 B0 = h2{(_Float16)v0.x, (_Float16)v0.y}, B1 = h2{(_Float16)v0.z, (_Float16)v0.w};
    h2 B2 = h2{(_Float16)v1_.x, (_Float16)v1_.y}, B3 = h2{(_Float16)v1_.z, (_Float16)v1_.w};
    h2 B4 = h2{(_Float16)v2_.x, (_Float16)v2_.y}, B5 = h2{(_Float16)v2_.z, (_Float16)v2_.w};
    h2 B6 = h2{(_Float16)v3_.x, (_Float16)v3_.y}, B7 = h2{(_Float16)v3_.z, (_Float16)v3_.w};
    h2 C0 = h2{(_Float16)t0.x, (_Float16)t0.y}, C1 = h2{(_Float16)t0.z, (_Float16)t0.w};
    h2 C2 = h2{(_Float16)t1.x, (_Float16)t1.y}, C3 = h2{(_Float16)t1.z, (_Float16)t1.w};
    h2 C4 = h2{(_Float16)t2.x, (_Float16)t2.y}, C5 = h2{(_Float16)t2.z, (_Float16)t2.w};
    h2 C6 = h2{(_Float16)t3.x, (_Float16)t3.y}, C7 = h2{(_Float16)t3.z, (_Float16)t3.w};

    // Quarter-scaled bias/input terms: butterfly sums 4 s-lanes -> full value.
    float wxq = W_ih0[row] * 0.25f;
    float bq0 = (b_ih0[row] + b_hh0[row]) * 0.25f;
    float bq1 = (b_ih1[row] + b_hh1[row]) * 0.25f;

    // Remat fence (R7-proven): weight data becomes opaque register values.
    asm volatile("" : "+v"(A0), "+v"(A1), "+v"(A2), "+v"(A3),
                      "+v"(A4), "+v"(A5), "+v"(A6), "+v"(A7),
                      "+v"(B0), "+v"(B1), "+v"(B2), "+v"(B3),
                      "+v"(B4), "+v"(B5), "+v"(B6), "+v"(B7),
                      "+v"(C0), "+v"(C1), "+v"(C2), "+v"(C3),
                      "+v"(C4), "+v"(C5), "+v"(C6), "+v"(C7),
                      "+v"(wxq), "+v"(bq0), "+v"(bq1));

    // Branchless activation constants: act(x) = mm * rcp(1 + exp(kk*x)) + aa.
    const bool isg = (jj == 2);
    const float kk = isg ? -2.f : -1.f;
    const float mm = isg ?  2.f :  1.f;
    const float aa = isg ? -1.f :  0.f;

    const bool wlane = ((lane & 13) == 0);     // jj==0 && ss even: h writer
    const int  hoff  = n + (ss << 5);          // ss=0 -> h0[n]; ss=2 -> h1[n]
    float cc = 0.f;                            // c0 in ss<2 lanes, c1 in ss>=2

    __syncthreads();

    for (int t = 0; t <= TT; ++t) {
        const float xt = x_s[(t < TT) ? t : 0];
        const h8* hb = (const h8*)hbuf[t & 1];
        h8 Ha = hb[2 * ss], Hb = hb[2 * ss + 1];         // h0 slice (16 halves)
        h8 Ga = hb[8 + 2 * ss], Gb = hb[9 + 2 * ss];     // h1 slice

        float acc0 = fmaf(xt, wxq, bq0);
        float acc1 = bq1;
        acc0 = FDOT2(A0, H2V(Ha, 0), acc0);
        acc0 = FDOT2(A1, H2V(Ha, 1), acc0);
        acc0 = FDOT2(A2, H2V(Ha, 2), acc0);
        acc0 = FDOT2(A3, H2V(Ha, 3), acc0);
        acc0 = FDOT2(A4, H2V(Hb, 0), acc0);
        acc0 = FDOT2(A5, H2V(Hb, 1), acc0);
        acc0 = FDOT2(A6, H2V(Hb, 2), acc0);
        acc0 = FDOT2(A7, H2V(Hb, 3), acc0);

        acc1 = FDOT2(B0, H2V(Ha, 0), acc1);
        acc1 = FDOT2(B1, H2V(Ha, 1), acc1);
        acc1 = FDOT2(B2, H2V(Ha, 2), acc1);
        acc1 = FDOT2(B3, H2V(Ha, 3), acc1);
        acc1 = FDOT2(B4, H2V(Hb, 0), acc1);
        acc1 = FDOT2(B5, H2V(Hb, 1), acc1);
        acc1 = FDOT2(B6, H2V(Hb, 2), acc1);
        acc1 = FDOT2(B7, H2V(Hb, 3), acc1);
        acc1 = FDOT2(C0, H2V(Ga, 0), acc1);
        acc1 = FDOT2(C1, H2V(Ga, 1), acc1);
        acc1 = FDOT2(C2, H2V(Ga, 2), acc1);
        acc1 = FDOT2(C3, H2V(Ga, 3), acc1);
        acc1 = FDOT2(C4, H2V(Gb, 0), acc1);
        acc1 = FDOT2(C5, H2V(Gb, 1), acc1);
        acc1 = FDOT2(C6, H2V(Gb, 2), acc1);
        acc1 = FDOT2(C7, H2V(Gb, 3), acc1);

        // s-butterfly (DPP, VALU): all 4 s-lanes get the full row sum.
        acc0 = dpp_add_xor1(acc0); acc0 = dpp_add_xor2(acc0);
        acc1 = dpp_add_xor1(acc1); acc1 = dpp_add_xor2(acc1);

        // Activations (branchless sig/tanh by per-lane consts).
        float e0 = __expf(kk * acc0);
        float act0 = fmaf(mm, __builtin_amdgcn_rcpf(1.f + e0), aa);
        float e1 = __expf(kk * acc1);
        float act1 = fmaf(mm, __builtin_amdgcn_rcpf(1.f + e1), aa);

        // Lane's layer: ss<2 -> L0 (time t), ss>=2 -> L1 (time t-1).
        float val = (ss < 2) ? act0 : act1;
        float g1 = __shfl_xor(val, 4);             // gate j+1 (for j=0: f)
        float g2 = __shfl_xor(val, 8);             // gate j+2 (for j=0: g)
        float g3 = __shfl_xor(g1, 8);              // gate j+3 (for j=0: o)

        // Cell update — valid only in jj==0 lanes (others carry garbage cc,
        // never read). i=val, f=g1, g=g2, o=g3.
        float cn = fmaf(g1, cc, val * g2);
        float hn = g3 * ftanh(cn);
        bool ok = (ss < 2) ? (t < TT) : (t > 0);   // L0 skip at TT, L1 at 0
        cc = ok ? cn : cc;
        if (wlane && ok) hbuf[(t + 1) & 1][hoff] = (_Float16)hn;

        __syncthreads();                           // h exchange (double-buffered)
    }

    // FC on final h1 = h1(TT-1), in hbuf[(TT+1)&1][64..128).
    if (tid < EE) {
        const _Float16* h1f = &hbuf[(TT + 1) & 1][HH];
        float acc = b_fc[tid];
        const float4* wf = (const float4*)(W_fc + tid * HH);
        #pragma unroll
        for (int k = 0; k < HH / 4; ++k) {
            float4 v = wf[k];
            acc = fmaf(v.x, (float)h1f[4*k+0], acc);
            acc = fmaf(v.y, (float)h1f[4*k+1], acc);
            acc = fmaf(v.z, (float)h1f[4*k+2], acc);
            acc = fmaf(v.w, (float)h1f[4*k+3], acc);
        }
        out[(size_t)b * EE + tid] = acc;
    }
}

extern "C" void kernel_launch(void* const* d_in, const int* in_sizes, int n_in,
                              void* d_out, int out_size, void* d_ws, size_t ws_size,
                              hipStream_t stream) {
    const float* x     = (const float*)d_in[0];
    const float* W_ih0 = (const float*)d_in[1];
    const float* W_hh0 = (const float*)d_in[2];
    const float* b_ih0 = (const float*)d_in[3];
    const float* b_hh0 = (const float*)d_in[4];
    const float* W_ih1 = (const float*)d_in[5];
    const float* W_hh1 = (const float*)d_in[6];
    const float* b_ih1 = (const float*)d_in[7];
    const float* b_hh1 = (const float*)d_in[8];
    const float* W_fc  = (const float*)d_in[9];
    const float* b_fc  = (const float*)d_in[10];
    float* out = (float*)d_out;

    lstm2_fc_kernel<<<dim3(NB), dim3(1024), 0, stream>>>(
        x, W_ih0, W_hh0, b_ih0, b_hh0, W_ih1, W_hh1, b_ih1, b_hh1, W_fc, b_fc, out);
}

// Round 9
// 2087.156 us; speedup vs baseline: 1.2973x; 1.1705x over previous
//
#include <hip/hip_runtime.h>

#define TT 4000   // timesteps
#define HH 64     // hidden
#define NB 256    // batch
#define EE 128    // fc out

typedef __attribute__((ext_vector_type(2))) _Float16 h2;
typedef __attribute__((ext_vector_type(8))) _Float16 h8;

__device__ __forceinline__ float ftanh(float x) {
    return fmaf(2.f, __builtin_amdgcn_rcpf(1.f + __expf(-2.f * x)), -1.f);
}

#if __has_builtin(__builtin_amdgcn_fdot2)
#define FDOT2(a, b, c) __builtin_amdgcn_fdot2((a), (b), (c), false)
#else
#define FDOT2(a, b, c) fmaf((float)(a).x, (float)(b).x, fmaf((float)(a).y, (float)(b).y, (c)))
#endif

// h2 sub-extract from h8 register (shufflevector -> sub-register, no memory).
#define H2V(V, i) (__builtin_shufflevector((V), (V), 2 * (i), 2 * (i) + 1))

// DPP quad-perm helpers (VALU pipe). 0xB1=[1,0,3,2] (xor1), 0x4E=[2,3,0,1] (xor2).
__device__ __forceinline__ float dpp_add_xor1(float v) {
    int m = __builtin_amdgcn_update_dpp(0, __float_as_int(v), 0xB1, 0xF, 0xF, true);
    return v + __int_as_float(m);
}
__device__ __forceinline__ float dpp_get_xor2(float v) {
    int m = __builtin_amdgcn_update_dpp(0, __float_as_int(v), 0x4E, 0xF, 0xF, true);
    return __int_as_float(m);
}
// xor lane^4 via ds_swizzle BitMode: (4<<10)|(0<<5)|31 = 0x101F.
__device__ __forceinline__ float swz_xor4(float v) {
    return __int_as_float(__builtin_amdgcn_ds_swizzle(__float_as_int(v), 0x101F));
}

#define CVT2(d0, d1, s) h2 d0 = h2{(_Float16)(s).x, (_Float16)(s).y}, \
                           d1 = h2{(_Float16)(s).z, (_Float16)(s).w};

// One block (512 thr) per batch element. tid = n*8 + j*2 + s:
//   n = h-index 0..63, j = gate (i,f,g,o), s = k-half (32 k each).
// R8 post-mortem: at 16 waves/block the kernel is VALU-ISSUE bound on
// redundant per-wave overhead (only 24/70 instr were dots; ~1010 cyc/step
// VALU at 1465 cyc/step). Dot issue floor is 192 cyc/SIMD/step; overhead
// scales with wave count -> halve waves, double dots/lane (48 fdot2, 48
// named h2 weights + R7-proven remat fence, ~95 VGPR).
// Redundant transcendentals drop 6 -> 4 per lane; gate gather = DPP xor2 +
// one ds_swizzle xor4 (replaces R8's shfl_xor(4)/shfl_xor(8)).
//
// Layer pipelining (verified R3-R8): iter t computes L0 gates(t) from h0(t-1)
// and L1 gates(t-1) from {h1(t-2), h0(t-1)}; s=0 lanes run L0 act/cell, s=1
// run L1. 1 barrier/step, h double-buffered.
__global__ __launch_bounds__(512, 2)
void lstm2_fc_kernel(const float* __restrict__ x,      // [B, T, 1]
                     const float* __restrict__ W_ih0,  // [256, 1]
                     const float* __restrict__ W_hh0,  // [256, 64]
                     const float* __restrict__ b_ih0,  // [256]
                     const float* __restrict__ b_hh0,  // [256]
                     const float* __restrict__ W_ih1,  // [256, 64]
                     const float* __restrict__ W_hh1,  // [256, 64]
                     const float* __restrict__ b_ih1,  // [256]
                     const float* __restrict__ b_hh1,  // [256]
                     const float* __restrict__ W_fc,   // [128, 64]
                     const float* __restrict__ b_fc,   // [128]
                     float* __restrict__ out)          // [B, 128]
{
    const int b   = blockIdx.x;
    const int tid = threadIdx.x;     // 0..511
    const int n   = tid >> 3;        // h-index 0..63
    const int jj  = (tid >> 1) & 3;  // gate
    const int ss  = tid & 1;         // k-half

    __shared__ float x_s[TT];                          // 16 KB
    __shared__ __align__(16) _Float16 hbuf[2][2 * HH]; // [parity][h0|h1], fp16

    for (int t = tid; t < TT; t += 512) x_s[t] = x[(size_t)b * TT + t];
    if (tid < 4 * HH) ((_Float16*)hbuf)[tid] = (_Float16)0.f;

    const int row = jj * HH + n;     // gate row in [0,256)
    // --- Named-scalar weight load: 3 thirty-two-wide slices -> 48 h2 ---
    const float4* p0 = (const float4*)(W_hh0 + row * HH + ss * 32);
    const float4* p1 = (const float4*)(W_ih1 + row * HH + ss * 32);
    const float4* p2 = (const float4*)(W_hh1 + row * HH + ss * 32);
    float4 a0 = p0[0], a1 = p0[1], a2 = p0[2], a3 = p0[3];
    float4 a4 = p0[4], a5 = p0[5], a6 = p0[6], a7 = p0[7];
    float4 e0 = p1[0], e1 = p1[1], e2 = p1[2], e3 = p1[3];
    float4 e4 = p1[4], e5 = p1[5], e6 = p1[6], e7 = p1[7];
    float4 d0 = p2[0], d1 = p2[1], d2 = p2[2], d3 = p2[3];
    float4 d4 = p2[4], d5 = p2[5], d6 = p2[6], d7 = p2[7];
    CVT2(A0,  A1,  a0) CVT2(A2,  A3,  a1) CVT2(A4,  A5,  a2) CVT2(A6,  A7,  a3)
    CVT2(A8,  A9,  a4) CVT2(A10, A11, a5) CVT2(A12, A13, a6) CVT2(A14, A15, a7)
    CVT2(B0,  B1,  e0) CVT2(B2,  B3,  e1) CVT2(B4,  B5,  e2) CVT2(B6,  B7,  e3)
    CVT2(B8,  B9,  e4) CVT2(B10, B11, e5) CVT2(B12, B13, e6) CVT2(B14, B15, e7)
    CVT2(C0,  C1,  d0) CVT2(C2,  C3,  d1) CVT2(C4,  C5,  d2) CVT2(C6,  C7,  d3)
    CVT2(C8,  C9,  d4) CVT2(C10, C11, d5) CVT2(C12, C13, d6) CVT2(C14, C15, d7)

    float wx  = W_ih0[row];
    float bb0 = b_ih0[row] + b_hh0[row];
    float bb1 = b_ih1[row] + b_hh1[row];

    // Remat fences (R7-proven; split to stay under asm operand limits).
    asm volatile("" : "+v"(A0), "+v"(A1), "+v"(A2),  "+v"(A3),
                      "+v"(A4), "+v"(A5), "+v"(A6),  "+v"(A7),
                      "+v"(A8), "+v"(A9), "+v"(A10), "+v"(A11),
                      "+v"(A12),"+v"(A13),"+v"(A14), "+v"(A15),
                      "+v"(B0), "+v"(B1), "+v"(B2),  "+v"(B3),
                      "+v"(B4), "+v"(B5), "+v"(B6),  "+v"(B7));
    asm volatile("" : "+v"(B8), "+v"(B9), "+v"(B10), "+v"(B11),
                      "+v"(B12),"+v"(B13),"+v"(B14), "+v"(B15),
                      "+v"(C0), "+v"(C1), "+v"(C2),  "+v"(C3),
                      "+v"(C4), "+v"(C5), "+v"(C6),  "+v"(C7),
                      "+v"(C8), "+v"(C9), "+v"(C10), "+v"(C11),
                      "+v"(C12),"+v"(C13),"+v"(C14), "+v"(C15),
                      "+v"(wx), "+v"(bb0),"+v"(bb1));

    // Branchless activation constants: act(z) = mm * rcp(1 + exp(kk*z)) + aa.
    const bool isg = (jj == 2);
    const float kk = isg ? -2.f : -1.f;
    const float mm = isg ?  2.f :  1.f;
    const float aa = isg ? -1.f :  0.f;

    const bool wlane = (jj == 0);          // h writer lanes
    const int  hoff  = ss * HH + n;        // s=0 -> h0[n], s=1 -> h1[n]
    float cc = 0.f;                        // c0 in s=0/j=0, c1 in s=1/j=0

    __syncthreads();

    for (int t = 0; t <= TT; ++t) {
        const float xt = x_s[(t < TT) ? t : 0];
        const h8* hb = (const h8*)hbuf[t & 1];
        // This lane's 32-half slices: h0 -> hb[4ss..4ss+3], h1 -> hb[8+4ss..].
        h8 Ha = hb[4 * ss + 0], Hc = hb[4 * ss + 1];
        h8 He = hb[4 * ss + 2], Hg = hb[4 * ss + 3];
        h8 Ga = hb[8 + 4 * ss + 0], Gc = hb[8 + 4 * ss + 1];
        h8 Ge = hb[8 + 4 * ss + 2], Gg = hb[8 + 4 * ss + 3];

        float acc0 = ss ? 0.f : fmaf(xt, wx, bb0);
        float acc1 = ss ? 0.f : bb1;
        acc0 = FDOT2(A0,  H2V(Ha, 0), acc0); acc0 = FDOT2(A1,  H2V(Ha, 1), acc0);
        acc0 = FDOT2(A2,  H2V(Ha, 2), acc0); acc0 = FDOT2(A3,  H2V(Ha, 3), acc0);
        acc0 = FDOT2(A4,  H2V(Hc, 0), acc0); acc0 = FDOT2(A5,  H2V(Hc, 1), acc0);
        acc0 = FDOT2(A6,  H2V(Hc, 2), acc0); acc0 = FDOT2(A7,  H2V(Hc, 3), acc0);
        acc0 = FDOT2(A8,  H2V(He, 0), acc0); acc0 = FDOT2(A9,  H2V(He, 1), acc0);
        acc0 = FDOT2(A10, H2V(He, 2), acc0); acc0 = FDOT2(A11, H2V(He, 3), acc0);
        acc0 = FDOT2(A12, H2V(Hg, 0), acc0); acc0 = FDOT2(A13, H2V(Hg, 1), acc0);
        acc0 = FDOT2(A14, H2V(Hg, 2), acc0); acc0 = FDOT2(A15, H2V(Hg, 3), acc0);

        acc1 = FDOT2(B0,  H2V(Ha, 0), acc1); acc1 = FDOT2(B1,  H2V(Ha, 1), acc1);
        acc1 = FDOT2(B2,  H2V(Ha, 2), acc1); acc1 = FDOT2(B3,  H2V(Ha, 3), acc1);
        acc1 = FDOT2(B4,  H2V(Hc, 0), acc1); acc1 = FDOT2(B5,  H2V(Hc, 1), acc1);
        acc1 = FDOT2(B6,  H2V(Hc, 2), acc1); acc1 = FDOT2(B7,  H2V(Hc, 3), acc1);
        acc1 = FDOT2(B8,  H2V(He, 0), acc1); acc1 = FDOT2(B9,  H2V(He, 1), acc1);
        acc1 = FDOT2(B10, H2V(He, 2), acc1); acc1 = FDOT2(B11, H2V(He, 3), acc1);
        acc1 = FDOT2(B12, H2V(Hg, 0), acc1); acc1 = FDOT2(B13, H2V(Hg, 1), acc1);
        acc1 = FDOT2(B14, H2V(Hg, 2), acc1); acc1 = FDOT2(B15, H2V(Hg, 3), acc1);
        acc1 = FDOT2(C0,  H2V(Ga, 0), acc1); acc1 = FDOT2(C1,  H2V(Ga, 1), acc1);
        acc1 = FDOT2(C2,  H2V(Ga, 2), acc1); acc1 = FDOT2(C3,  H2V(Ga, 3), acc1);
        acc1 = FDOT2(C4,  H2V(Gc, 0), acc1); acc1 = FDOT2(C5,  H2V(Gc, 1), acc1);
        acc1 = FDOT2(C6,  H2V(Gc, 2), acc1); acc1 = FDOT2(C7,  H2V(Gc, 3), acc1);
        acc1 = FDOT2(C8,  H2V(Ge, 0), acc1); acc1 = FDOT2(C9,  H2V(Ge, 1), acc1);
        acc1 = FDOT2(C10, H2V(Ge, 2), acc1); acc1 = FDOT2(C11, H2V(Ge, 3), acc1);
        acc1 = FDOT2(C12, H2V(Gg, 0), acc1); acc1 = FDOT2(C13, H2V(Gg, 1), acc1);
        acc1 = FDOT2(C14, H2V(Gg, 2), acc1); acc1 = FDOT2(C15, H2V(Gg, 3), acc1);

        // s-butterfly (DPP): both s-lanes get full row sums.
        acc0 = dpp_add_xor1(acc0);
        acc1 = dpp_add_xor1(acc1);

        // Per-lane layer: s=0 -> L0(t), s=1 -> L1(t-1). One activation each.
        float z  = ss ? acc1 : acc0;
        float ez = __expf(kk * z);
        float val = fmaf(mm, __builtin_amdgcn_rcpf(1.f + ez), aa);

        // Gate gather: lanes j differ in bits 1-2. x2=v(j^1), x4=v(j^2), x6=v(j^3).
        float x2 = dpp_get_xor2(val);
        float x4 = swz_xor4(val);
        float x6 = swz_xor4(x2);

        // Cell update — valid in j==0 lanes (i=val, f=x2, g=x4, o=x6).
        float cn = fmaf(x2, cc, val * x4);
        float hn = x6 * ftanh(cn);
        bool ok = ss ? (t > 0) : (t < TT);       // L1 skip at 0, L0 at TT
        cc = (wlane && ok) ? cn : cc;
        if (wlane && ok) hbuf[(t + 1) & 1][hoff] = (_Float16)hn;

        __syncthreads();                         // h exchange (double-buffered)
    }

    // FC on final h1 = h1(TT-1), in hbuf[(TT+1)&1][64..128).
    if (tid < EE) {
        const _Float16* h1f = &hbuf[(TT + 1) & 1][HH];
        float acc = b_fc[tid];
        const float4* wf = (const float4*)(W_fc + tid * HH);
        #pragma unroll
        for (int k = 0; k < HH / 4; ++k) {
            float4 v = wf[k];
            acc = fmaf(v.x, (float)h1f[4*k+0], acc);
            acc = fmaf(v.y, (float)h1f[4*k+1], acc);
            acc = fmaf(v.z, (float)h1f[4*k+2], acc);
            acc = fmaf(v.w, (float)h1f[4*k+3], acc);
        }
        out[(size_t)b * EE + tid] = acc;
    }
}

extern "C" void kernel_launch(void* const* d_in, const int* in_sizes, int n_in,
                              void* d_out, int out_size, void* d_ws, size_t ws_size,
                              hipStream_t stream) {
    const float* x     = (const float*)d_in[0];
    const float* W_ih0 = (const float*)d_in[1];
    const float* W_hh0 = (const float*)d_in[2];
    const float* b_ih0 = (const float*)d_in[3];
    const float* b_hh0 = (const float*)d_in[4];
    const float* W_ih1 = (const float*)d_in[5];
    const float* W_hh1 = (const float*)d_in[6];
    const float* b_ih1 = (const float*)d_in[7];
    const float* b_hh1 = (const float*)d_in[8];
    const float* W_fc  = (const float*)d_in[9];
    const float* b_fc  = (const float*)d_in[10];
    float* out = (float*)d_out;

    lstm2_fc_kernel<<<dim3(NB), dim3(512), 0, stream>>>(
        x, W_ih0, W_hh0, b_ih0, b_hh0, W_ih1, W_hh1, b_ih1, b_hh1, W_fc, b_fc, out);
}